// Round 1
// baseline (317.733 us; speedup 1.0000x reference)
//
#include <hip/hip_runtime.h>

#define NR 131072
#define DD 32
#define KK 64
#define BETA_C 10.0f

// ---------------------------------------------------------------------------
// ws layout (float-indexed):
//   [0,64)            fill_g      (float, atomic accum of softmax p sums)
//   [64,128)          counts_g    (int)
//   [128,2176)        sums_g      (float, K*D)
//   [2176,67712)      m2_g        (float, K*D*D)
//   [67712,198784)    pred_g      (int, N)
// memset covers the first 67712 floats each launch (ws is re-poisoned 0xAA).
// ---------------------------------------------------------------------------

// phase 1: per-row distances to all 64 centers, softmax-filling accumulation,
// hard argmin prediction. One row per thread; grid sized exactly NR/256 so the
// wave-level shuffles below are always fully populated.
__global__ __launch_bounds__(256) void phase1_kernel(
    const float* __restrict__ x, const float* __restrict__ centers,
    float* __restrict__ fill_g, int* __restrict__ pred_g) {
  __shared__ float4 cS[KK * 8];   // centers, float4-packed (8 KB)
  __shared__ float cnS[KK];       // ||c_k||^2
  __shared__ float fillW[4][KK];  // per-wave filling accumulators

  const int tid = threadIdx.x;
  const int lane = tid & 63;
  const int wid = tid >> 6;

  for (int i = tid; i < KK * 8; i += 256) cS[i] = ((const float4*)centers)[i];
  ((float*)fillW)[tid] = 0.0f;
  __syncthreads();
  if (tid < KK) {
    float s = 0.f;
#pragma unroll
    for (int j = 0; j < 8; ++j) {
      float4 c = cS[tid * 8 + j];
      s += c.x * c.x + c.y * c.y + c.z * c.z + c.w * c.w;
    }
    cnS[tid] = s;
  }
  __syncthreads();

  const int row = blockIdx.x * 256 + tid;  // grid == NR/256 exactly

  float4 xr[8];
  const float4* xp = (const float4*)(x + (size_t)row * DD);
#pragma unroll
  for (int j = 0; j < 8; ++j) xr[j] = xp[j];
  float xx = 0.f;
#pragma unroll
  for (int j = 0; j < 8; ++j)
    xx += xr[j].x * xr[j].x + xr[j].y * xr[j].y + xr[j].z * xr[j].z + xr[j].w * xr[j].w;

  // d2v kept fully unrolled -> stays in VGPRs (dynamic index would spill)
  float d2v[KK];
  float best = 3.4e38f;
  int bi = 0;
#pragma unroll
  for (int k = 0; k < KK; ++k) {
    float dot = 0.f;
#pragma unroll
    for (int j = 0; j < 8; ++j) {
      float4 c = cS[k * 8 + j];  // wave-uniform address -> LDS broadcast, free
      dot += xr[j].x * c.x + xr[j].y * c.y + xr[j].z * c.z + xr[j].w * c.w;
    }
    float d2 = xx - 2.0f * dot + cnS[k];  // same formula as reference
    d2v[k] = d2;
    if (d2 < best) { best = d2; bi = k; }  // strict < == first-index tie-break
  }
  pred_g[row] = bi;

  float ssum = 0.f;
#pragma unroll
  for (int k = 0; k < KK; ++k) {
    float e = __expf(BETA_C * (best - d2v[k]));  // arg <= 0, no overflow
    d2v[k] = e;
    ssum += e;
  }
  const float inv = 1.0f / ssum;

  // wave-reduce p_k across 64 lanes (64 rows), lane 0 accumulates per wave
#pragma unroll
  for (int k = 0; k < KK; ++k) {
    float v = d2v[k] * inv;
    v += __shfl_xor(v, 32, 64);
    v += __shfl_xor(v, 16, 64);
    v += __shfl_xor(v, 8, 64);
    v += __shfl_xor(v, 4, 64);
    v += __shfl_xor(v, 2, 64);
    v += __shfl_xor(v, 1, 64);
    if (lane == 0) fillW[wid][k] += v;
  }

  __syncthreads();
  if (tid < KK)
    atomicAdd(&fill_g[tid],
              fillW[0][tid] + fillW[1][tid] + fillW[2][tid] + fillW[3][tid]);
}

// phase 3: gather-SYRK. grid = KK * CH blocks; block handles (cluster k,
// row-chunk c): scans pred, compacts matching row indices, gathers rows into
// LDS, accumulates C = sum x x^T in a 2x2 register tile per thread, plus
// per-cluster counts and sums. One global-atomic flush per block at the end.
#define CH 8
#define RPB (NR / CH)  // 16384 rows per block
#define ITR 4096       // rows scanned per compaction iteration

__global__ __launch_bounds__(256) void phase3_kernel(
    const float* __restrict__ x, const int* __restrict__ pred_g,
    int* __restrict__ counts_g, float* __restrict__ sums_g,
    float* __restrict__ m2_g) {
  __shared__ int idxList[ITR];      // worst case: every scanned row matches
  __shared__ float xs[64 * DD];     // gathered row tile (8 KB)
  __shared__ int cntS;

  const int tid = threadIdx.x;
  const int k = blockIdx.x & (KK - 1);
  const int chunk = blockIdx.x >> 6;
  const int rowBase = chunk * RPB;

  const int ti = tid >> 4, tj = tid & 15;
  const int i0 = ti, i1 = ti + 16, j0 = tj, j1 = tj + 16;
  float c00 = 0.f, c01 = 0.f, c10 = 0.f, c11 = 0.f;
  float sd = 0.f;  // column sum, threads 0..31
  int totalM = 0;

  for (int it = 0; it < RPB / ITR; ++it) {
    if (tid == 0) cntS = 0;
    __syncthreads();
    const int ibase = rowBase + it * ITR;
#pragma unroll
    for (int q = 0; q < ITR / 1024; ++q) {
      const int r0 = ibase + q * 1024 + tid * 4;
      const int4 p4 = *(const int4*)(pred_g + r0);  // coalesced
      if (p4.x == k) idxList[atomicAdd(&cntS, 1)] = r0;
      if (p4.y == k) idxList[atomicAdd(&cntS, 1)] = r0 + 1;
      if (p4.z == k) idxList[atomicAdd(&cntS, 1)] = r0 + 2;
      if (p4.w == k) idxList[atomicAdd(&cntS, 1)] = r0 + 3;
    }
    __syncthreads();
    const int m = cntS;  // uniform across block
    totalM += m;
    for (int off = 0; off < m; off += 64) {
      const int cnt = min(64, m - off);
      __syncthreads();  // previous tile's readers done before overwrite
      for (int e = tid; e < cnt * DD; e += 256) {
        const int r = idxList[off + (e >> 5)];
        xs[e] = x[(size_t)r * DD + (e & 31)];  // 128B segments
      }
      __syncthreads();
      for (int r = 0; r < cnt; ++r) {
        const float* xrp = xs + r * DD;
        // all LDS reads below are same-address broadcasts within lane groups
        const float a0 = xrp[i0], a1 = xrp[i1];
        const float b0 = xrp[j0], b1 = xrp[j1];
        c00 += a0 * b0;
        c01 += a0 * b1;
        c10 += a1 * b0;
        c11 += a1 * b1;
        if (tid < DD) sd += xrp[tid];
      }
    }
  }

  float* m2k = m2_g + k * (DD * DD);
  atomicAdd(&m2k[i0 * DD + j0], c00);
  atomicAdd(&m2k[i0 * DD + j1], c01);
  atomicAdd(&m2k[i1 * DD + j0], c10);
  atomicAdd(&m2k[i1 * DD + j1], c11);
  if (tid < DD) atomicAdd(&sums_g[k * DD + tid], sd);
  if (tid == 0) atomicAdd(&counts_g[k], totalM);
}

// finalize: all three loss terms, block reduce, scalar out.
__global__ __launch_bounds__(256) void finalize_kernel(
    const float* __restrict__ fill_g, const int* __restrict__ counts_g,
    const float* __restrict__ sums_g, const float* __restrict__ m2_g,
    const float* __restrict__ ft, const float* __restrict__ mt,
    const float* __restrict__ ct, float* __restrict__ out) {
  __shared__ float meansS[KK * DD];
  __shared__ float invDenS[KK];
  __shared__ float wred[4];
  const int t = threadIdx.x;

  if (t < KK) invDenS[t] = 1.0f / fmaxf((float)counts_g[t], 1.0f);
  __syncthreads();

  float accM = 0.f;
  for (int e = t; e < KK * DD; e += 256) {
    const float mean = sums_g[e] * invDenS[e >> 5];
    meansS[e] = mean;
    const float d = mean - mt[e];
    accM += d * d;
  }
  __syncthreads();

  float accC = 0.f;
  for (int e = t; e < KK * DD * DD; e += 256) {
    const int kk = e >> 10;
    const float mi = meansS[e >> 5];                       // k*32 + i
    const float mj = meansS[((e >> 10) << 5) | (e & 31)];  // k*32 + j
    const float cov = m2_g[e] * invDenS[kk] - mi * mj;
    const float d = cov - ct[e];
    accC += d * d;
  }

  float accF = 0.f;
  if (t < KK) {
    const float f = fill_g[t] * (1.0f / (float)NR) - ft[t];
    accF = f * f;
  }

  float v = accF * (1.0f / KK) + accM * (1.0f / (KK * DD)) +
            accC * (1.0f / (KK * DD * DD));
  v += __shfl_xor(v, 32, 64);
  v += __shfl_xor(v, 16, 64);
  v += __shfl_xor(v, 8, 64);
  v += __shfl_xor(v, 4, 64);
  v += __shfl_xor(v, 2, 64);
  v += __shfl_xor(v, 1, 64);
  if ((t & 63) == 0) wred[t >> 6] = v;
  __syncthreads();
  if (t == 0) out[0] = wred[0] + wred[1] + wred[2] + wred[3];
}

extern "C" void kernel_launch(void* const* d_in, const int* in_sizes, int n_in,
                              void* d_out, int out_size, void* d_ws,
                              size_t ws_size, hipStream_t stream) {
  (void)in_sizes; (void)n_in; (void)out_size; (void)ws_size;
  const float* x = (const float*)d_in[0];
  const float* centers = (const float*)d_in[1];
  const float* ft = (const float*)d_in[2];
  const float* mt = (const float*)d_in[3];
  const float* ct = (const float*)d_in[4];
  float* out = (float*)d_out;

  float* ws = (float*)d_ws;
  float* fill_g = ws;                    // 64
  int* counts_g = (int*)(ws + 64);       // 64
  float* sums_g = ws + 128;              // 2048
  float* m2_g = ws + 2176;               // 65536
  int* pred_g = (int*)(ws + 67712);      // 131072

  // zero the accumulators (fill/counts/sums/m2); pred is fully overwritten
  hipMemsetAsync(d_ws, 0, (size_t)67712 * sizeof(float), stream);

  phase1_kernel<<<NR / 256, 256, 0, stream>>>(x, centers, fill_g, pred_g);
  phase3_kernel<<<KK * CH, 256, 0, stream>>>(x, pred_g, counts_g, sums_g, m2_g);
  finalize_kernel<<<1, 256, 0, stream>>>(fill_g, counts_g, sums_g, m2_g, ft, mt,
                                         ct, out);
}

// Round 2
// 191.784 us; speedup vs baseline: 1.6567x; 1.6567x over previous
//
#include <hip/hip_runtime.h>

#define NR 131072
#define DD 32
#define KK 64
#define BETA_C 10.0f

// ---------------------------------------------------------------------------
// ws layout (float-indexed):
//   [0,64)        fill_g   (float, atomic accum of softmax p sums)
//   [64,128)      counts_g (int)
//   [128,132)     lossAcc  (float scalar, atomic)
//   [192,2240)    sums_g   (float, K*D)
//   [2240,67776)  m2_g     (float, K*D*D; only lower triangle i>=j written)
//   [67776,...)   pred_g   (int, N)
// memset zeroes the first 67776 floats each launch (ws re-poisoned 0xAA).
// ---------------------------------------------------------------------------

// phase 1: per-row distances to all 64 centers, softmax-filling accumulation,
// hard argmin prediction. One row per thread; grid == NR/256 exactly.
__global__ __launch_bounds__(256) void phase1_kernel(
    const float* __restrict__ x, const float* __restrict__ centers,
    float* __restrict__ fill_g, int* __restrict__ pred_g) {
  __shared__ float4 cS[KK * 8];   // centers, float4-packed (8 KB)
  __shared__ float cnS[KK];       // ||c_k||^2
  __shared__ float fillW[4][KK];  // per-wave filling accumulators

  const int tid = threadIdx.x;
  const int lane = tid & 63;
  const int wid = tid >> 6;

  for (int i = tid; i < KK * 8; i += 256) cS[i] = ((const float4*)centers)[i];
  ((float*)fillW)[tid] = 0.0f;
  __syncthreads();
  if (tid < KK) {
    float s = 0.f;
#pragma unroll
    for (int j = 0; j < 8; ++j) {
      float4 c = cS[tid * 8 + j];
      s += c.x * c.x + c.y * c.y + c.z * c.z + c.w * c.w;
    }
    cnS[tid] = s;
  }
  __syncthreads();

  const int row = blockIdx.x * 256 + tid;

  float4 xr[8];
  const float4* xp = (const float4*)(x + (size_t)row * DD);
#pragma unroll
  for (int j = 0; j < 8; ++j) xr[j] = xp[j];
  float xx = 0.f;
#pragma unroll
  for (int j = 0; j < 8; ++j)
    xx += xr[j].x * xr[j].x + xr[j].y * xr[j].y + xr[j].z * xr[j].z + xr[j].w * xr[j].w;

  float d2v[KK];  // fully unrolled -> stays in VGPRs
  float best = 3.4e38f;
  int bi = 0;
#pragma unroll
  for (int k = 0; k < KK; ++k) {
    float dot = 0.f;
#pragma unroll
    for (int j = 0; j < 8; ++j) {
      float4 c = cS[k * 8 + j];  // wave-uniform address -> LDS broadcast
      dot += xr[j].x * c.x + xr[j].y * c.y + xr[j].z * c.z + xr[j].w * c.w;
    }
    float d2 = xx - 2.0f * dot + cnS[k];
    d2v[k] = d2;
    if (d2 < best) { best = d2; bi = k; }  // strict < == first-index tie-break
  }
  pred_g[row] = bi;

  float ssum = 0.f;
#pragma unroll
  for (int k = 0; k < KK; ++k) {
    float e = __expf(BETA_C * (best - d2v[k]));  // arg <= 0, no overflow
    d2v[k] = e;
    ssum += e;
  }
  const float inv = 1.0f / ssum;

#pragma unroll
  for (int k = 0; k < KK; ++k) {
    float v = d2v[k] * inv;
    v += __shfl_xor(v, 32, 64);
    v += __shfl_xor(v, 16, 64);
    v += __shfl_xor(v, 8, 64);
    v += __shfl_xor(v, 4, 64);
    v += __shfl_xor(v, 2, 64);
    v += __shfl_xor(v, 1, 64);
    if (lane == 0) fillW[wid][k] += v;
  }

  __syncthreads();
  if (tid < KK)
    atomicAdd(&fill_g[tid],
              fillW[0][tid] + fillW[1][tid] + fillW[2][tid] + fillW[3][tid]);
}

// phase 3 v2: gather-SYRK, lower-triangle only.
// grid = KK*CH blocks; block (k, chunk) scans its 4096 preds with ballot
// compaction (local ushort indices), gathers matching rows into LDS in
// 64-row tiles, accumulates c00/c10/c11 (2x2 tile minus the mirrored c01)
// with a 4-row unroll, then flushes lower-triangle atomics.
#define CH 32
#define RPB (NR / CH)  // 4096 rows per block

__global__ __launch_bounds__(256) void phase3_kernel(
    const float* __restrict__ x, const int* __restrict__ pred_g,
    int* __restrict__ counts_g, float* __restrict__ sums_g,
    float* __restrict__ m2_g) {
  __shared__ unsigned short idxList[RPB];  // local row offsets (8 KB worst)
  __shared__ float xs[64 * DD];            // gathered row tile (8 KB)
  __shared__ int cntS;

  const int tid = threadIdx.x;
  const int lane = tid & 63;
  const int k = blockIdx.x & (KK - 1);
  const int chunk = blockIdx.x >> 6;
  const int base = chunk * RPB;

  if (tid == 0) cntS = 0;
  __syncthreads();

  // ---- scan + wave-ballot compaction (1 LDS atomic per wave-round) ----
  const int4* pp = (const int4*)(pred_g + base);
  int4 pv[4];
#pragma unroll
  for (int q = 0; q < 4; ++q) pv[q] = pp[tid + 256 * q];
#pragma unroll
  for (int q = 0; q < 4; ++q) {
    const int l0 = (tid + 256 * q) * 4;  // local row offset of .x
    const int pr[4] = {pv[q].x, pv[q].y, pv[q].z, pv[q].w};
#pragma unroll
    for (int c = 0; c < 4; ++c) {
      const bool match = (pr[c] == k);
      const unsigned long long mask = __ballot(match);
      const int tot = __popcll(mask);
      const int pre = __builtin_amdgcn_mbcnt_hi(
          (unsigned)(mask >> 32),
          __builtin_amdgcn_mbcnt_lo((unsigned)mask, 0));
      int b = 0;
      if (lane == 0 && tot) b = atomicAdd(&cntS, tot);
      b = __shfl(b, 0, 64);
      if (match) idxList[b + pre] = (unsigned short)(l0 + c);
    }
  }
  __syncthreads();
  const int m = cntS;  // uniform

  const int ti = tid >> 4, tj = tid & 15;
  const int i0 = ti, i1 = ti + 16, j0 = tj, j1 = tj + 16;
  float c00 = 0.f, c10 = 0.f, c11 = 0.f;
  const int scol = tid & 31, srow0 = tid >> 5;
  float sd = 0.f;

  for (int off = 0; off < m; off += 64) {
    const int cnt = min(64, m - off);
    __syncthreads();  // previous tile's readers done before overwrite
    for (int e = tid; e < cnt * DD; e += 256) {
      const int r = base + (int)idxList[off + (e >> 5)];
      xs[e] = x[(size_t)r * DD + (e & 31)];  // 128B row segments
    }
    __syncthreads();
    // column sums (all 256 threads, 8 rows apart)
    for (int r = srow0; r < cnt; r += 8) sd += xs[r * DD + scol];
    // rank-1 updates, 4-row unroll; all LDS reads are broadcast groups
    int r = 0;
    for (; r + 4 <= cnt; r += 4) {
#pragma unroll
      for (int u = 0; u < 4; ++u) {
        const float* xrp = xs + (r + u) * DD;
        const float a0 = xrp[i0], a1 = xrp[i1];
        const float b0 = xrp[j0], b1 = xrp[j1];
        c00 += a0 * b0;
        c10 += a1 * b0;
        c11 += a1 * b1;
      }
    }
    for (; r < cnt; ++r) {
      const float* xrp = xs + r * DD;
      const float a0 = xrp[i0], a1 = xrp[i1];
      const float b0 = xrp[j0], b1 = xrp[j1];
      c00 += a0 * b0;
      c10 += a1 * b0;
      c11 += a1 * b1;
    }
  }

  // lower-triangle flush: (i1,j0) always lower; (i0,j0)/(i1,j1) iff tj<=ti.
  float* m2k = m2_g + k * (DD * DD);
  atomicAdd(&m2k[i1 * DD + j0], c10);
  if (tj <= ti) {
    atomicAdd(&m2k[i0 * DD + j0], c00);
    atomicAdd(&m2k[i1 * DD + j1], c11);
  }
  atomicAdd(&sums_g[k * DD + scol], sd);
  if (tid == 0) atomicAdd(&counts_g[k], m);
}

// finalize A: one block per cluster; all three loss terms -> atomic scalar.
__global__ __launch_bounds__(256) void finalizeA_kernel(
    const float* __restrict__ fill_g, const int* __restrict__ counts_g,
    const float* __restrict__ sums_g, const float* __restrict__ m2_g,
    const float* __restrict__ ft, const float* __restrict__ mt,
    const float* __restrict__ ct, float* __restrict__ lossAcc) {
  __shared__ float meanS[DD];
  __shared__ float wred[4];
  const int t = threadIdx.x;
  const int k = blockIdx.x;

  const float inv = 1.0f / fmaxf((float)counts_g[k], 1.0f);
  if (t < DD) meanS[t] = sums_g[k * DD + t] * inv;
  __syncthreads();

  float acc = 0.f;
  if (t < DD) {
    const float d = meanS[t] - mt[k * DD + t];
    acc += d * d * (1.0f / (KK * DD));
  }
  if (t == 0) {
    const float f = fill_g[k] * (1.0f / (float)NR) - ft[k];
    acc += f * f * (1.0f / KK);
  }
  const float* m2k = m2_g + k * (DD * DD);
  const float* ctk = ct + k * (DD * DD);
#pragma unroll
  for (int u = 0; u < 4; ++u) {
    const int e = t + 256 * u;  // coalesced ct reads
    const int i = e >> 5, j = e & 31;
    const float val = (i >= j) ? m2k[i * DD + j] : m2k[j * DD + i];  // mirror
    const float cov = val * inv - meanS[i] * meanS[j];
    const float d = cov - ctk[e];
    acc += d * d * (1.0f / (KK * DD * DD));
  }

  acc += __shfl_xor(acc, 32, 64);
  acc += __shfl_xor(acc, 16, 64);
  acc += __shfl_xor(acc, 8, 64);
  acc += __shfl_xor(acc, 4, 64);
  acc += __shfl_xor(acc, 2, 64);
  acc += __shfl_xor(acc, 1, 64);
  if ((t & 63) == 0) wred[t >> 6] = acc;
  __syncthreads();
  if (t == 0) atomicAdd(lossAcc, wred[0] + wred[1] + wred[2] + wred[3]);
}

// finalize B: copy the accumulated scalar to d_out.
__global__ void finalizeB_kernel(const float* __restrict__ lossAcc,
                                 float* __restrict__ out) {
  if (threadIdx.x == 0) out[0] = lossAcc[0];
}

extern "C" void kernel_launch(void* const* d_in, const int* in_sizes, int n_in,
                              void* d_out, int out_size, void* d_ws,
                              size_t ws_size, hipStream_t stream) {
  (void)in_sizes; (void)n_in; (void)out_size; (void)ws_size;
  const float* x = (const float*)d_in[0];
  const float* centers = (const float*)d_in[1];
  const float* ft = (const float*)d_in[2];
  const float* mt = (const float*)d_in[3];
  const float* ct = (const float*)d_in[4];
  float* out = (float*)d_out;

  float* ws = (float*)d_ws;
  float* fill_g = ws;                 // 64
  int* counts_g = (int*)(ws + 64);    // 64
  float* lossAcc = ws + 128;          // 1 (+pad)
  float* sums_g = ws + 192;           // 2048
  float* m2_g = ws + 2240;            // 65536 -> ends 67776
  int* pred_g = (int*)(ws + 67776);   // 131072

  hipMemsetAsync(d_ws, 0, (size_t)67776 * sizeof(float), stream);

  phase1_kernel<<<NR / 256, 256, 0, stream>>>(x, centers, fill_g, pred_g);
  phase3_kernel<<<KK * CH, 256, 0, stream>>>(x, pred_g, counts_g, sums_g, m2_g);
  finalizeA_kernel<<<KK, 256, 0, stream>>>(fill_g, counts_g, sums_g, m2_g, ft,
                                           mt, ct, lossAcc);
  finalizeB_kernel<<<1, 64, 0, stream>>>(lossAcc, out);
}

// Round 3
// 150.265 us; speedup vs baseline: 2.1145x; 1.2763x over previous
//
#include <hip/hip_runtime.h>

#define NR 131072
#define DD 32
#define KK 64
#define BETA_C 10.0f

// ---------------------------------------------------------------------------
// ws layout (float-indexed):
//   [0,64)        fill_g   (float, atomic accum of softmax p sums)
//   [64,128)      counts_g (int)
//   [128,132)     lossAcc  (float scalar, atomic)
//   [192,2240)    sums_g   (float, K*D)
//   [2240,67776)  m2_g     (float, K*D*D; only lower triangle i>=j written)
//   [67776,...)   pred_g   (int, N)
// memset zeroes the first 67776 floats each launch (ws re-poisoned 0xAA).
// ---------------------------------------------------------------------------

// phase 1 v3: centers read via wave-uniform global loads (-> s_load, scalar
// cache; deletes the 512 ds_read_b128/thread of v2) and a 63-shuffle
// recursive-halving transpose-reduce (v2 used 384 shuffles). One row/thread.
__global__ __launch_bounds__(256) void phase1_kernel(
    const float* __restrict__ x, const float* __restrict__ centers,
    float* __restrict__ fill_g, int* __restrict__ pred_g) {
  __shared__ float cnS[KK];       // ||c_k||^2
  __shared__ float fillW[4][KK];  // per-wave filling results

  const int tid = threadIdx.x;
  const int lane = tid & 63;
  const int wid = tid >> 6;

  if (tid < KK) {
    float s = 0.f;
    const float* cp = centers + tid * DD;
#pragma unroll
    for (int j = 0; j < DD; ++j) s += cp[j] * cp[j];
    cnS[tid] = s;
  }
  __syncthreads();

  const int row = blockIdx.x * 256 + tid;  // grid == NR/256 exactly

  float xr[DD];  // row in VGPRs (compile-time indexed throughout)
  const float4* xp = (const float4*)(x + (size_t)row * DD);
#pragma unroll
  for (int j = 0; j < 8; ++j) {
    const float4 v = xp[j];
    xr[4 * j + 0] = v.x;
    xr[4 * j + 1] = v.y;
    xr[4 * j + 2] = v.z;
    xr[4 * j + 3] = v.w;
  }
  float xx = 0.f;
#pragma unroll
  for (int j = 0; j < DD; ++j) xx += xr[j] * xr[j];

  float pv[KK];  // d2, then p; fully unrolled -> VGPRs
  float best = 3.4e38f;
  int bi = 0;
#pragma unroll
  for (int k = 0; k < KK; ++k) {
    float dot = 0.f;
#pragma unroll
    for (int j = 0; j < DD; ++j)
      dot += xr[j] * centers[k * DD + j];  // uniform addr -> s_load (K$)
    const float d2 = xx - 2.0f * dot + cnS[k];  // same formula as reference
    pv[k] = d2;
    if (d2 < best) { best = d2; bi = k; }  // strict < == first-index tie-break
  }
  pred_g[row] = bi;

  float ssum = 0.f;
#pragma unroll
  for (int k = 0; k < KK; ++k) {
    const float e = __expf(BETA_C * (best - pv[k]));  // arg <= 0, no overflow
    pv[k] = e;
    ssum += e;
  }
  const float inv = 1.0f / ssum;
#pragma unroll
  for (int k = 0; k < KK; ++k) pv[k] *= inv;

  // recursive-halving transpose-reduce: 63 shuffles total; afterwards lane l
  // holds sum over the wave's 64 rows of p[l] (k bits assembled from lane
  // bits, stage by stage).
#pragma unroll
  for (int m = 32; m >= 1; m >>= 1) {
    const bool hi = (lane & m) != 0;
#pragma unroll
    for (int i = 0; i < m; ++i) {
      const float send = hi ? pv[i] : pv[i + m];  // half the partner keeps
      const float recv = __shfl_xor(send, m, 64);
      const float keep = hi ? pv[i + m] : pv[i];
      pv[i] = keep + recv;
    }
  }
  fillW[wid][lane] = pv[0];
  __syncthreads();
  if (tid < KK)
    atomicAdd(&fill_g[tid],
              fillW[0][tid] + fillW[1][tid] + fillW[2][tid] + fillW[3][tid]);
}

// phase 3: gather-SYRK, lower-triangle only (unchanged from R2).
#define CH 32
#define RPB (NR / CH)  // 4096 rows per block

__global__ __launch_bounds__(256) void phase3_kernel(
    const float* __restrict__ x, const int* __restrict__ pred_g,
    int* __restrict__ counts_g, float* __restrict__ sums_g,
    float* __restrict__ m2_g) {
  __shared__ unsigned short idxList[RPB];  // local row offsets (8 KB worst)
  __shared__ float xs[64 * DD];            // gathered row tile (8 KB)
  __shared__ int cntS;

  const int tid = threadIdx.x;
  const int lane = tid & 63;
  const int k = blockIdx.x & (KK - 1);
  const int chunk = blockIdx.x >> 6;
  const int base = chunk * RPB;

  if (tid == 0) cntS = 0;
  __syncthreads();

  // scan + wave-ballot compaction (1 LDS atomic per wave-round)
  const int4* pp = (const int4*)(pred_g + base);
  int4 pv[4];
#pragma unroll
  for (int q = 0; q < 4; ++q) pv[q] = pp[tid + 256 * q];
#pragma unroll
  for (int q = 0; q < 4; ++q) {
    const int l0 = (tid + 256 * q) * 4;
    const int pr[4] = {pv[q].x, pv[q].y, pv[q].z, pv[q].w};
#pragma unroll
    for (int c = 0; c < 4; ++c) {
      const bool match = (pr[c] == k);
      const unsigned long long mask = __ballot(match);
      const int tot = __popcll(mask);
      const int pre = __builtin_amdgcn_mbcnt_hi(
          (unsigned)(mask >> 32),
          __builtin_amdgcn_mbcnt_lo((unsigned)mask, 0));
      int b = 0;
      if (lane == 0 && tot) b = atomicAdd(&cntS, tot);
      b = __shfl(b, 0, 64);
      if (match) idxList[b + pre] = (unsigned short)(l0 + c);
    }
  }
  __syncthreads();
  const int m = cntS;  // uniform

  const int ti = tid >> 4, tj = tid & 15;
  const int i0 = ti, i1 = ti + 16, j0 = tj, j1 = tj + 16;
  float c00 = 0.f, c10 = 0.f, c11 = 0.f;
  const int scol = tid & 31, srow0 = tid >> 5;
  float sd = 0.f;

  for (int off = 0; off < m; off += 64) {
    const int cnt = min(64, m - off);
    __syncthreads();  // previous tile's readers done before overwrite
    for (int e = tid; e < cnt * DD; e += 256) {
      const int r = base + (int)idxList[off + (e >> 5)];
      xs[e] = x[(size_t)r * DD + (e & 31)];  // 128B row segments
    }
    __syncthreads();
    for (int r = srow0; r < cnt; r += 8) sd += xs[r * DD + scol];
    int r = 0;
    for (; r + 4 <= cnt; r += 4) {
#pragma unroll
      for (int u = 0; u < 4; ++u) {
        const float* xrp = xs + (r + u) * DD;
        const float a0 = xrp[i0], a1 = xrp[i1];
        const float b0 = xrp[j0], b1 = xrp[j1];
        c00 += a0 * b0;
        c10 += a1 * b0;
        c11 += a1 * b1;
      }
    }
    for (; r < cnt; ++r) {
      const float* xrp = xs + r * DD;
      const float a0 = xrp[i0], a1 = xrp[i1];
      const float b0 = xrp[j0], b1 = xrp[j1];
      c00 += a0 * b0;
      c10 += a1 * b0;
      c11 += a1 * b1;
    }
  }

  float* m2k = m2_g + k * (DD * DD);
  atomicAdd(&m2k[i1 * DD + j0], c10);
  if (tj <= ti) {
    atomicAdd(&m2k[i0 * DD + j0], c00);
    atomicAdd(&m2k[i1 * DD + j1], c11);
  }
  atomicAdd(&sums_g[k * DD + scol], sd);
  if (tid == 0) atomicAdd(&counts_g[k], m);
}

// finalize A: one block per cluster; all three loss terms -> atomic scalar.
__global__ __launch_bounds__(256) void finalizeA_kernel(
    const float* __restrict__ fill_g, const int* __restrict__ counts_g,
    const float* __restrict__ sums_g, const float* __restrict__ m2_g,
    const float* __restrict__ ft, const float* __restrict__ mt,
    const float* __restrict__ ct, float* __restrict__ lossAcc) {
  __shared__ float meanS[DD];
  __shared__ float wred[4];
  const int t = threadIdx.x;
  const int k = blockIdx.x;

  const float inv = 1.0f / fmaxf((float)counts_g[k], 1.0f);
  if (t < DD) meanS[t] = sums_g[k * DD + t] * inv;
  __syncthreads();

  float acc = 0.f;
  if (t < DD) {
    const float d = meanS[t] - mt[k * DD + t];
    acc += d * d * (1.0f / (KK * DD));
  }
  if (t == 0) {
    const float f = fill_g[k] * (1.0f / (float)NR) - ft[k];
    acc += f * f * (1.0f / KK);
  }
  const float* m2k = m2_g + k * (DD * DD);
  const float* ctk = ct + k * (DD * DD);
#pragma unroll
  for (int u = 0; u < 4; ++u) {
    const int e = t + 256 * u;  // coalesced ct reads
    const int i = e >> 5, j = e & 31;
    const float val = (i >= j) ? m2k[i * DD + j] : m2k[j * DD + i];  // mirror
    const float cov = val * inv - meanS[i] * meanS[j];
    const float d = cov - ctk[e];
    acc += d * d * (1.0f / (KK * DD * DD));
  }

  acc += __shfl_xor(acc, 32, 64);
  acc += __shfl_xor(acc, 16, 64);
  acc += __shfl_xor(acc, 8, 64);
  acc += __shfl_xor(acc, 4, 64);
  acc += __shfl_xor(acc, 2, 64);
  acc += __shfl_xor(acc, 1, 64);
  if ((t & 63) == 0) wred[t >> 6] = acc;
  __syncthreads();
  if (t == 0) atomicAdd(lossAcc, wred[0] + wred[1] + wred[2] + wred[3]);
}

// finalize B: copy the accumulated scalar to d_out.
__global__ void finalizeB_kernel(const float* __restrict__ lossAcc,
                                 float* __restrict__ out) {
  if (threadIdx.x == 0) out[0] = lossAcc[0];
}

extern "C" void kernel_launch(void* const* d_in, const int* in_sizes, int n_in,
                              void* d_out, int out_size, void* d_ws,
                              size_t ws_size, hipStream_t stream) {
  (void)in_sizes; (void)n_in; (void)out_size; (void)ws_size;
  const float* x = (const float*)d_in[0];
  const float* centers = (const float*)d_in[1];
  const float* ft = (const float*)d_in[2];
  const float* mt = (const float*)d_in[3];
  const float* ct = (const float*)d_in[4];
  float* out = (float*)d_out;

  float* ws = (float*)d_ws;
  float* fill_g = ws;                 // 64
  int* counts_g = (int*)(ws + 64);    // 64
  float* lossAcc = ws + 128;          // 1 (+pad)
  float* sums_g = ws + 192;           // 2048
  float* m2_g = ws + 2240;            // 65536 -> ends 67776
  int* pred_g = (int*)(ws + 67776);   // 131072

  hipMemsetAsync(d_ws, 0, (size_t)67776 * sizeof(float), stream);

  phase1_kernel<<<NR / 256, 256, 0, stream>>>(x, centers, fill_g, pred_g);
  phase3_kernel<<<KK * CH, 256, 0, stream>>>(x, pred_g, counts_g, sums_g, m2_g);
  finalizeA_kernel<<<KK, 256, 0, stream>>>(fill_g, counts_g, sums_g, m2_g, ft,
                                           mt, ct, lossAcc);
  finalizeB_kernel<<<1, 64, 0, stream>>>(lossAcc, out);
}